// Round 10
// baseline (86.209 us; speedup 1.0000x reference)
//
#include <hip/hip_runtime.h>
#include <math.h>

// ---------------------------------------------------------------------------
// ScatteringNetwork:
//   img [8,1,256,256] f32, psi_re/psi_im [10,1,11,11] f32, blur_k [7,7] f32
//   out: concat([s0(1ch), s1_out(10ch), s2_out(100ch)]) at 32x32 -> [8, 111*1024]
//
// blur(conv(x,psi))[::8] == conv(x, psi (*) blur)[::8]. blur = g (x) g and
// psi_k = F_k (x) H_k (both rank-1 exact) -> composed 17x17 kernel is rank-2:
// comb_k = F'r(x)H'r - F'i(x)H'i, F' = a (*) F, H' = b (*) H. Blur-pad clip at
// Y==0 / X==0 only clips a / b -> variant factors F'' / H'' (rare paths).
//
// R10: k_main6 hoists BOTH tasks' 11 float4 row loads ahead of all FMAs and
// pins them with sched_barrier(0) (R9's VGPR=48 showed the compiler re-sank
// the loads -> ~22 serialized L2 round-trips/lane). launch_bounds(320,3)
// raises the VGPR cap to ~170 so xv[2][11] (88 VGPR) stays live.
//
// ws layout (floats):
//   [0)        pimg   : 8  * 272*272 = 591,872   (img padded, zero border 8)
//   [591872)   s1p    : 80 * 272*272 = 5,918,720 (s1abs padded)
//   [6510592)  fhp    : 10*136
// fhp per ch: [0)H'r [17)H'i [34)H''r [51)H''i [68)F'r [85)F'i [102)F''r [119)F''i
// ---------------------------------------------------------------------------

#define PIMG_SZ  73984          // 272*272
#define PIMG_OFF 0
#define S1P_OFF  591872
#define FHP_OFF  6510592

// ---------------- k_s1: separable Morlet |conv|, wave-per-channel ----------
__global__ __launch_bounds__(640) void k_s1(const float* __restrict__ img,
                                            const float* __restrict__ psi_re,
                                            const float* __restrict__ psi_im,
                                            const float* __restrict__ blur,
                                            float* __restrict__ pimg,
                                            float* __restrict__ s1p,
                                            float* __restrict__ fhp) {
    if (blockIdx.z == 8) {        // setup slice: fhp + pimg copy + s1p borders
        int bid = blockIdx.y * 16 + blockIdx.x;       // 0..255
        int tid = threadIdx.x;
        if (bid == 0) {
            for (int g = tid; g < 1360; g += 640) {
                int ch = g / 136;
                int w = g - ch * 136;
                int part = w / 17;
                int i = w - part * 17;
                const float* pr = psi_re + ch * 121;
                const float* pi = psi_im + ch * 121;
                float val = 0.f;
                if (part < 4) {                       // H-type: H_j = psi[5][j]
                    int qmin = (part >= 2) ? 3 : 0;
                    int comp = part & 1;
                    float bden = blur[24];
                    for (int q = qmin; q < 7; ++q) {
                        int jj = i - q;
                        if (jj < 0 || jj > 10) continue;
                        float bq = blur[21 + q] / bden;
                        float hh = comp ? pi[55 + jj] : pr[55 + jj];
                        val += bq * hh;
                    }
                } else {                              // F-type: F_i = psi[i][5]/psi[5][5]
                    int pmin = (part >= 6) ? 3 : 0;
                    int comp = part & 1;
                    float dr = pr[60], di = pi[60];
                    float inv = 1.f / (dr * dr + di * di);
                    for (int p = pmin; p < 7; ++p) {
                        int ii = i - p;
                        if (ii < 0 || ii > 10) continue;
                        float ap = blur[p * 7 + 3];
                        float nr = pr[ii * 11 + 5], ni = pi[ii * 11 + 5];
                        float f = comp ? (ni * dr - nr * di) * inv
                                       : (nr * dr + ni * di) * inv;
                        val += ap * f;
                    }
                }
                fhp[g] = val;
            }
        } else if (bid <= 32) {
            // pimg copy (float4): image n, row-quarter q of the 272 padded rows
            int n = (bid - 1) >> 2;
            int q = (bid - 1) & 3;
            float* dst = pimg + n * PIMG_SZ;
            const float* src = img + n * 65536;
            for (int idx = tid; idx < 68 * 68; idx += 640) {
                int pr = 68 * q + idx / 68;
                int c4 = idx - (idx / 68) * 68;
                float4 v = {0.f, 0.f, 0.f, 0.f};
                if (pr >= 8 && pr < 264 && c4 >= 2 && c4 < 66)
                    v = *(const float4*)(src + (pr - 8) * 256 + (4 * c4 - 8));
                *(float4*)(dst + pr * 272 + 4 * c4) = v;
            }
        } else if (bid <= 72) {
            // s1p border zero: 2 channel-images per block, 8448 border cells each
            int u = (bid - 33) * 2;
            for (int k = u; k < u + 2; ++k) {
                float* base = s1p + (size_t)k * PIMG_SZ;
                for (int e = tid; e < 8448; e += 640) {
                    int row, col;
                    if (e < 2176) {            // top 8 rows
                        row = e / 272; col = e - row * 272;
                    } else if (e < 4352) {     // bottom 8 rows
                        int e2 = e - 2176;
                        int r2 = e2 / 272;
                        row = 264 + r2; col = e2 - r2 * 272;
                    } else {                   // left/right 8-col strips
                        int e2 = e - 4352;
                        row = 8 + (e2 >> 4);
                        int cc = e2 & 15;
                        col = (cc < 8) ? cc : 256 + cc;
                    }
                    base[row * 272 + col] = 0.f;
                }
            }
        }
        return;
    }

    __shared__ float timg[26 * 27];
    __shared__ float inter[10][26 * 34];
    int tid = threadIdx.x;
    int lane = tid & 63;
    int c = __builtin_amdgcn_readfirstlane(tid >> 6);   // wave = channel 0..9

    const float* pr = psi_re + c * 121;
    const float* pi = psi_im + c * 121;
    float hr[11], hi[11], fr[11], fi[11];
#pragma unroll
    for (int j = 0; j < 11; ++j) { hr[j] = pr[55 + j]; hi[j] = pi[55 + j]; }
#pragma unroll
    for (int i = 0; i < 11; ++i) { fr[i] = pr[i * 11 + 5]; fi[i] = pi[i * 11 + 5]; }
    float dr = pr[60], di = pi[60];
    float inv = rsqrtf(dr * dr + di * di);

    int n = blockIdx.z;
    int y0 = blockIdx.y * 16, x0 = blockIdx.x * 16;
    const float* im = img + n * 65536;
    for (int idx = tid; idx < 676; idx += 640) {
        int r = idx / 26, cc = idx - r * 26;
        int gy = y0 + r - 5, gx = x0 + cc - 5;
        timg[r * 27 + cc] = (gy >= 0 && gy < 256 && gx >= 0 && gx < 256) ? im[gy * 256 + gx] : 0.f;
    }
    __syncthreads();

    int rr = lane >> 1;
    int half = lane & 1;
    if (rr < 26) {
        int cx0 = half * 8;
        float xv[18];
#pragma unroll
        for (int t = 0; t < 18; ++t) xv[t] = timg[rr * 27 + cx0 + t];
#pragma unroll
        for (int m = 0; m < 8; ++m) {
            float ar = 0.f, ai = 0.f;
#pragma unroll
            for (int j = 0; j < 11; ++j) {
                ar = fmaf(hr[j], xv[m + j], ar);
                ai = fmaf(hi[j], xv[m + j], ai);
            }
            inter[c][rr * 34 + 2 * (cx0 + m)]     = ar;
            inter[c][rr * 34 + 2 * (cx0 + m) + 1] = ai;
        }
    }
    __syncthreads();

    int x = lane & 15, yq = lane >> 4;
    int yb = 4 * yq;
    const float* sc = &inter[c][yb * 34 + 2 * x];
    float accr[4] = {0.f, 0.f, 0.f, 0.f};
    float acci[4] = {0.f, 0.f, 0.f, 0.f};
#pragma unroll
    for (int r = 0; r < 14; ++r) {
        float vr = sc[r * 34], vi = sc[r * 34 + 1];
#pragma unroll
        for (int dy = 0; dy < 4; ++dy) {
            if (r - dy >= 0 && r - dy <= 10) {
                float wr = fr[r - dy], wi = fi[r - dy];
                accr[dy] = fmaf(wr, vr, fmaf(-wi, vi, accr[dy]));
                acci[dy] = fmaf(wr, vi, fmaf(wi, vr, acci[dy]));
            }
        }
    }
    float* so = s1p + (size_t)(n * 10 + c) * PIMG_SZ + (8 + y0 + yb) * 272 + (8 + x0 + x);
#pragma unroll
    for (int dy = 0; dy < 4; ++dy)
        so[dy * 272] = inv * sqrtf(accr[dy] * accr[dy] + acci[dy] * acci[dy]);
}

// ---------------- k_main6: rank-2 separable composed conv ------------------
// grid (32 = 16 Ybands x 2 Xhalves, 11 src, 8 n), 320 thr = 5 waves x 2 ch.
// Both tasks' row loads issued up-front and pinned with sched_barrier(0).
__global__ __launch_bounds__(320, 3) void k_main6(const float* __restrict__ pimg,
                                                  const float* __restrict__ s1p,
                                                  const float* __restrict__ fhp,
                                                  const float* __restrict__ blur,
                                                  float* __restrict__ out) {
    __shared__ __align__(16) float inter[10][900];   // 36 KB
    int tid = threadIdx.x;
    int bx = blockIdx.x;
    int b = bx >> 1, h = bx & 1;   // Y in {2b,2b+1}, X in [16h,16h+16)
    int src = blockIdx.y;          // 0..10
    int n = blockIdx.z;

    const float* sp = (src == 0) ? pimg + n * PIMG_SZ
                                 : s1p + (size_t)(n * 10 + src - 1) * PIMG_SZ;

    int wave = __builtin_amdgcn_readfirstlane(tid >> 6);
    int lane = tid & 63;
    int chA = wave, chB = wave + 5;
    const float* fA = fhp + chA * 136;   // uniform -> s_load (SGPR weights)
    const float* fB = fhp + chB * 136;
    float HrA[9], HiA[9], HrB[9], HiB[9];
#pragma unroll
    for (int j = 0; j < 9; ++j) {
        HrA[j] = fA[j]; HiA[j] = fA[17 + j];
        HrB[j] = fB[j]; HiB[j] = fB[17 + j];
    }
    // col-pass F' preload (per-lane, issued early to overlap row pass)
    int q = lane >> 5;
    int ysub = (lane >> 4) & 1;
    int Xc = lane & 15;
    const float* fq = q ? fB : fA;
    float Fr[9], Fi[9];
#pragma unroll
    for (int i = 0; i < 9; ++i) { Fr[i] = fq[68 + i]; Fi[i] = fq[85 + i]; }

    float* iA = &inter[wave * 2][0];
    float* iB = &inter[wave * 2 + 1][0];

    // ---- row pass: 100 tasks (rr 0..24, xr 0..3), <=2 per lane ----
    // Phase 1: issue ALL loads (22 float4/lane), pinned before any FMA.
    float4 xv[2][11];
    int rrs[2], xrs[2];
    bool act[2];
#pragma unroll
    for (int it = 0; it < 2; ++it) {
        int t = lane + 64 * it;
        act[it] = (t < 100);
        rrs[it] = t >> 2;
        xrs[it] = t & 3;
        if (act[it]) {
            const float* trow = sp + (16 * b + rrs[it]) * 272 + 128 * h + 32 * xrs[it];
#pragma unroll
            for (int mc = 0; mc < 11; ++mc)
                xv[it][mc] = *(const float4*)(trow + 4 * mc);
        }
    }
    __builtin_amdgcn_sched_barrier(0);   // loads may not sink past this point

    // Phase 2: FMA both tasks.
#pragma unroll
    for (int it = 0; it < 2; ++it) {
        if (act[it]) {
            float aR[4] = {0.f,0.f,0.f,0.f}, aI[4] = {0.f,0.f,0.f,0.f};
            float bR[4] = {0.f,0.f,0.f,0.f}, bI[4] = {0.f,0.f,0.f,0.f};
#pragma unroll
            for (int mc = 0; mc < 11; ++mc) {
#pragma unroll
                for (int e = 0; e < 4; ++e) {
                    int cidx = 4 * mc + e;
                    float x = (&xv[it][mc].x)[e];
#pragma unroll
                    for (int w = 0; w < 4; ++w) {
                        int j = cidx - 8 * w;
                        if (j >= 0 && j <= 16) {           // static after unroll
                            int jm = (j < 9) ? j : 16 - j;
                            aR[w] = fmaf(HrA[jm], x, aR[w]);
                            aI[w] = fmaf((j < 9) ? HiA[jm] : -HiA[jm], x, aI[w]);
                            bR[w] = fmaf(HrB[jm], x, bR[w]);
                            bI[w] = fmaf((j < 9) ? HiB[jm] : -HiB[jm], x, bI[w]);
                        }
                    }
                }
            }
            float* dA = iA + rrs[it] * 36 + 8 * xrs[it];
            float* dB = iB + rrs[it] * 36 + 8 * xrs[it];
            float4 a0 = {aR[0], aI[0], aR[1], aI[1]};
            float4 a1 = {aR[2], aI[2], aR[3], aI[3]};
            float4 b0 = {bR[0], bI[0], bR[1], bI[1]};
            float4 b1 = {bR[2], bI[2], bR[3], bI[3]};
            *(float4*)dA = a0; *(float4*)(dA + 4) = a1;
            *(float4*)dB = b0; *(float4*)(dB + 4) = b1;
        }
    }

    // X global == 0 slot redo with clipped H'' (h==0 blocks; weights uniform)
    if (h == 0 && lane < 25) {
        int rr = lane;
        const float* trow0 = sp + (16 * b + rr) * 272;   // padded cols 0..16
        float sRA = 0.f, sIA = 0.f, sRB = 0.f, sIB = 0.f;
#pragma unroll
        for (int j = 0; j < 17; ++j) {
            float x = trow0[j];
            sRA = fmaf(fA[34 + j], x, sRA);
            sIA = fmaf(fA[51 + j], x, sIA);
            sRB = fmaf(fB[34 + j], x, sRB);
            sIB = fmaf(fB[51 + j], x, sIB);
        }
        iA[rr * 36] = sRA; iA[rr * 36 + 1] = sIA;
        iB[rr * 36] = sRB; iB[rr * 36 + 1] = sIB;
    }
    __syncthreads();

    // col pass: lane = (q:2, ysub:2, Xc:16) -> one output each
    int Y = 2 * b + ysub;
    const float* isl = q ? iB : iA;
    float acc = 0.f;
#pragma unroll
    for (int i = 0; i < 17; ++i) {
        float vr = isl[(8 * ysub + i) * 36 + 2 * Xc];
        float vi = isl[(8 * ysub + i) * 36 + 2 * Xc + 1];
        int im_ = (i < 9) ? i : 16 - i;
        float fr_ = Fr[im_];
        float fi_ = (i < 9) ? Fi[im_] : -Fi[im_];
        acc = fmaf(fr_, vr, acc);
        acc = fmaf(-fi_, vi, acc);
    }
    if (Y == 0) {                 // b==0 blocks (1/16): clipped F'' recompute
        acc = 0.f;
#pragma unroll
        for (int i = 0; i < 17; ++i) {
            float vr = isl[i * 36 + 2 * Xc];
            float vi = isl[i * 36 + 2 * Xc + 1];
            acc = fmaf(fq[102 + i], vr, acc);
            acc = fmaf(-fq[119 + i], vi, acc);
        }
    }
    int ch = q ? chB : chA;
    int ch_out = (src == 0) ? 1 + ch : 11 + (src - 1) * 10 + ch;
    size_t nb = (size_t)n * 111 * 1024;
    out[nb + (size_t)ch_out * 1024 + Y * 32 + 16 * h + Xc] = acc;

    // s0: exact clipped 7x7 blur at stride 8, from padded img
    if (src == 0 && wave == 0 && lane < 32) {
        int ys = lane >> 4, Xs = lane & 15;
        const float* pim = pimg + n * PIMG_SZ;
        float s0 = 0.f;
#pragma unroll
        for (int p = 0; p < 7; ++p)
#pragma unroll
            for (int qq = 0; qq < 7; ++qq)
                s0 = fmaf(blur[p * 7 + qq],
                          pim[(16 * b + 8 * ys + p + 5) * 272 + 128 * h + 8 * Xs + qq + 5], s0);
        out[nb + (2 * b + ys) * 32 + 16 * h + Xs] = s0;
    }
}

extern "C" void kernel_launch(void* const* d_in, const int* in_sizes, int n_in,
                              void* d_out, int out_size, void* d_ws, size_t ws_size,
                              hipStream_t stream) {
    const float* img    = (const float*)d_in[0];
    const float* psi_re = (const float*)d_in[1];
    const float* psi_im = (const float*)d_in[2];
    const float* blur   = (const float*)d_in[3];
    float* out = (float*)d_out;
    float* ws = (float*)d_ws;
    float* pimg = ws + PIMG_OFF;
    float* s1p  = ws + S1P_OFF;
    float* fhp  = ws + FHP_OFF;

    dim3 g1(16, 16, 9);
    k_s1<<<g1, 640, 0, stream>>>(img, psi_re, psi_im, blur, pimg, s1p, fhp);

    dim3 g2(32, 11, 8);
    k_main6<<<g2, 320, 0, stream>>>(pimg, s1p, fhp, blur, out);
}

// Round 12
// 76.053 us; speedup vs baseline: 1.1335x; 1.1335x over previous
//
#include <hip/hip_runtime.h>
#include <math.h>

// ---------------------------------------------------------------------------
// ScatteringNetwork:
//   img [8,1,256,256] f32, psi_re/psi_im [10,1,11,11] f32, blur_k [7,7] f32
//   out: concat([s0(1ch), s1_out(10ch), s2_out(100ch)]) at 32x32 -> [8, 111*1024]
//
// blur(conv(x,psi))[::8] == conv(x, psi (*) blur)[::8]; blur = g(x)g and
// psi_k = F_k (x) H_k (rank-1 exact) -> composed 17x17 kernel is rank-2:
// comb_k = F'r(x)H'r - F'i(x)H'i. Y==0/X==0 blur-pad clip -> F''/H'' variants.
//
// R12 = R11 mega-fusion + row-padding fix: s1buf rows with img row outside
// [0,255] must be ZERO (the composed conv's zero-pad of s1abs), not the
// conv's analytic continuation. One predicate added (ry bounds).
//
// ws: [0) fhp 10*136 floats only.
// fhp per ch: [0)H'r [17)H'i [34)H''r [51)H''i [68)F'r [85)F'i [102)F''r [119)F''i
// ---------------------------------------------------------------------------

// ---------------- k_fhp: composed factor table (validated R6-R10) ----------
__global__ void k_fhp(const float* __restrict__ psi_re,
                      const float* __restrict__ psi_im,
                      const float* __restrict__ blur,
                      float* __restrict__ fhp) {
    int g = blockIdx.x * 64 + threadIdx.x;
    if (g >= 1360) return;
    int ch = g / 136;
    int w = g - ch * 136;
    int part = w / 17;
    int i = w - part * 17;
    const float* pr = psi_re + ch * 121;
    const float* pi = psi_im + ch * 121;
    float val = 0.f;
    if (part < 4) {                       // H-type: H_j = psi[5][j]
        int qmin = (part >= 2) ? 3 : 0;
        int comp = part & 1;
        float bden = blur[24];
        for (int q = qmin; q < 7; ++q) {
            int jj = i - q;
            if (jj < 0 || jj > 10) continue;
            float bq = blur[21 + q] / bden;
            float hh = comp ? pi[55 + jj] : pr[55 + jj];
            val += bq * hh;
        }
    } else {                              // F-type: F_i = psi[i][5]/psi[5][5]
        int pmin = (part >= 6) ? 3 : 0;
        int comp = part & 1;
        float dr = pr[60], di = pi[60];
        float inv = 1.f / (dr * dr + di * di);
        for (int p = pmin; p < 7; ++p) {
            int ii = i - p;
            if (ii < 0 || ii > 10) continue;
            float ap = blur[p * 7 + 3];
            float nr = pr[ii * 11 + 5], ni = pi[ii * 11 + 5];
            float f = comp ? (ni * dr - nr * di) * inv
                           : (nr * dr + ni * di) * inv;
            val += ap * f;
        }
    }
    fhp[g] = val;
}

// ---------------- k_fused: whole network, one block per (Y, src, n) --------
// grid (32, 11, 8), 512 threads. LDS: bufA 7236 f (strip/s1buf),
// bufB 9112 f (Iv/Cbuf) -> 65392 B -> 2 blocks/CU.
__global__ __launch_bounds__(512, 2) void k_fused(const float* __restrict__ img,
                                                  const float* __restrict__ psi_re,
                                                  const float* __restrict__ psi_im,
                                                  const float* __restrict__ blur,
                                                  const float* __restrict__ fhp,
                                                  float* __restrict__ out) {
    __shared__ float lds[16348];
    float* bufA = lds;          // img strip, later s1buf
    float* bufB = lds + 7236;   // Iv, later Cbuf
    const int tid = threadIdx.x;
    const int Y = blockIdx.x;   // 0..31
    const int src = blockIdx.y; // 0..10
    const int n = blockIdx.z;
    const float* im = img + n * 65536;
    size_t nb = (size_t)n * 111 * 1024;

    if (src == 0) {
        // ---- s0 + s1_out path: img strip [17][274], rows 8Y-8.., cols -8..263
        for (int i = tid; i < 17 * 274; i += 512) {
            int r = i / 274, c = i - r * 274;
            int gr = 8 * Y - 8 + r, gc = c - 8;
            float v = 0.f;
            if (gr >= 0 && gr < 256 && gc >= 0 && gc < 256 && c < 272)
                v = im[gr * 256 + gc];
            bufA[i] = v;
        }
        __syncthreads();
        // C_k(x) = sum_i F'_k(i) * strip(i, x)   (Y==0 -> F'')
        if (tid < 272) {
            int x = tid;
            float v[17];
#pragma unroll
            for (int i = 0; i < 17; ++i) v[i] = bufA[i * 274 + x];
            int sw = 2 * x + 2 * (x >> 4);
#pragma unroll
            for (int k = 0; k < 10; ++k) {
                const float* fR = fhp + k * 136 + ((Y == 0) ? 102 : 68);  // s_load
                const float* fI = fhp + k * 136 + ((Y == 0) ? 119 : 85);
                float cr = 0.f, ci = 0.f;
#pragma unroll
                for (int i = 0; i < 17; ++i) {
                    cr = fmaf(fR[i], v[i], cr);
                    ci = fmaf(fI[i], v[i], ci);
                }
                bufB[k * 576 + sw] = cr;
                bufB[k * 576 + sw + 1] = ci;
            }
        }
        __syncthreads();
        if (tid < 320) {        // out row: 10 ch x 32 X
            int k = tid >> 5, X = tid & 31;
            const float* hb = fhp + k * 136 + ((X == 0) ? 34 : 0);
            float hwr[17], hwi[17];
#pragma unroll
            for (int j = 0; j < 17; ++j) { hwr[j] = hb[j]; hwi[j] = hb[17 + j]; }
            float acc = 0.f;
#pragma unroll
            for (int j = 0; j < 17; ++j) {
                int x = 8 * X + j;
                int sw = 2 * x + 2 * (x >> 4);
                acc = fmaf(hwr[j], bufB[k * 576 + sw], acc);
                acc = fmaf(-hwi[j], bufB[k * 576 + sw + 1], acc);
            }
            out[nb + (size_t)(1 + k) * 1024 + Y * 32 + X] = acc;
        } else if (tid < 352) { // s0: direct clipped 7x7 blur at stride 8
            int X = tid - 320;
            float s0 = 0.f;
#pragma unroll
            for (int p = 0; p < 7; ++p)
#pragma unroll
                for (int q = 0; q < 7; ++q)
                    s0 = fmaf(blur[p * 7 + q], bufA[(p + 5) * 274 + 8 * X + q + 5], s0);
            out[nb + Y * 32 + X] = s0;
        }
        return;
    }

    // ---- s2 path for group g = src-1 ----
    int g = src - 1;
    const float* pr = psi_re + g * 121;   // block-uniform -> s_load weights
    const float* pi = psi_im + g * 121;
    float dr = pr[60], di = pi[60];
    float inv = rsqrtf(dr * dr + di * di);

    // stage img strip [27][268], rows 8Y-13.., cols -5..260
    for (int i = tid; i < 27 * 268; i += 512) {
        int r = i / 268, c = i - r * 268;
        int gr = 8 * Y - 13 + r, gc = c - 5;
        float v = 0.f;
        if (gr >= 0 && gr < 256 && gc >= 0 && gc < 256 && c < 266)
            v = im[gr * 256 + gc];
        bufA[i] = v;
    }
    __syncthreads();

    // Iv(r,ci) = sum_p F_raw(p) * strip(r+p, ci)  (complex), r<17, ci<266
    for (int t = tid; t < 17 * 266; t += 512) {
        int r = t / 266, ci = t - r * 266;
        float ar = 0.f, ai = 0.f;
#pragma unroll
        for (int p = 0; p < 11; ++p) {
            float x = bufA[(r + p) * 268 + ci];
            ar = fmaf(pr[p * 11 + 5], x, ar);
            ai = fmaf(pi[p * 11 + 5], x, ai);
        }
        bufB[(r * 268 + ci) * 2] = ar;
        bufB[(r * 268 + ci) * 2 + 1] = ai;
    }
    __syncthreads();

    // s1buf[17][272] = inv*|sum_j H_raw(j)*Iv(r, x+j)|, x-pad 8 zeros/side.
    // R12 FIX: rows whose img row ry=8Y-8+r is outside [0,255] must be ZERO
    // (zero-padding of s1abs in the composed conv), not the conv continuation.
    for (int t = tid; t < 17 * 272; t += 512) {
        int r = t / 272, cs = t - r * 272;
        int ry = 8 * Y - 8 + r;
        float val = 0.f;
        if (cs >= 8 && cs < 264 && ry >= 0 && ry < 256) {
            int x = cs - 8;
            const float* ivp = bufB + (r * 268 + x) * 2;
            float sr = 0.f, si = 0.f;
#pragma unroll
            for (int j = 0; j < 11; ++j) {
                float hr = pr[55 + j], hi2 = pi[55 + j];
                float vr = ivp[2 * j], vi2 = ivp[2 * j + 1];
                sr = fmaf(hr, vr, fmaf(-hi2, vi2, sr));
                si = fmaf(hr, vi2, fmaf(hi2, vr, si));
            }
            val = inv * sqrtf(sr * sr + si * si);
        }
        bufA[t] = val;
    }
    __syncthreads();

    // C_k(x) = sum_i F'_k(i) * s1buf(i, x)  (Cbuf overlays Iv)
    if (tid < 272) {
        int x = tid;
        float v[17];
#pragma unroll
        for (int i = 0; i < 17; ++i) v[i] = bufA[i * 272 + x];
        int sw = 2 * x + 2 * (x >> 4);
#pragma unroll
        for (int k = 0; k < 10; ++k) {
            const float* fR = fhp + k * 136 + ((Y == 0) ? 102 : 68);  // s_load
            const float* fI = fhp + k * 136 + ((Y == 0) ? 119 : 85);
            float cr = 0.f, ci = 0.f;
#pragma unroll
            for (int i = 0; i < 17; ++i) {
                cr = fmaf(fR[i], v[i], cr);
                ci = fmaf(fI[i], v[i], ci);
            }
            bufB[k * 576 + sw] = cr;
            bufB[k * 576 + sw + 1] = ci;
        }
    }
    __syncthreads();

    // out(k, X) = sum_j [H'r(j)*Cr - H'i(j)*Ci] at x = 8X+j  (X==0 -> H'')
    if (tid < 320) {
        int k = tid >> 5, X = tid & 31;
        const float* hb = fhp + k * 136 + ((X == 0) ? 34 : 0);
        float hwr[17], hwi[17];
#pragma unroll
        for (int j = 0; j < 17; ++j) { hwr[j] = hb[j]; hwi[j] = hb[17 + j]; }
        float acc = 0.f;
#pragma unroll
        for (int j = 0; j < 17; ++j) {
            int x = 8 * X + j;
            int sw = 2 * x + 2 * (x >> 4);
            acc = fmaf(hwr[j], bufB[k * 576 + sw], acc);
            acc = fmaf(-hwi[j], bufB[k * 576 + sw + 1], acc);
        }
        out[nb + (size_t)(11 + g * 10 + k) * 1024 + Y * 32 + X] = acc;
    }
}

extern "C" void kernel_launch(void* const* d_in, const int* in_sizes, int n_in,
                              void* d_out, int out_size, void* d_ws, size_t ws_size,
                              hipStream_t stream) {
    const float* img    = (const float*)d_in[0];
    const float* psi_re = (const float*)d_in[1];
    const float* psi_im = (const float*)d_in[2];
    const float* blur   = (const float*)d_in[3];
    float* out = (float*)d_out;
    float* fhp = (float*)d_ws;

    k_fhp<<<22, 64, 0, stream>>>(psi_re, psi_im, blur, fhp);

    dim3 g2(32, 11, 8);
    k_fused<<<g2, 512, 0, stream>>>(img, psi_re, psi_im, blur, fhp, out);
}